// Round 9
// baseline (110.628 us; speedup 1.0000x reference)
//
#include <hip/hip_runtime.h>
#include <math.h>

#define BLK 256
#define NCLS 22
#define EPSF 1.1920929e-07f
#define K1PAIRS 2
#define K1CHUNK (BLK * 2 * K1PAIRS)   // 1024 rows per k1 block

__device__ __constant__ float c_lo[6] = {0.f, 15.f, 30.f, 60.f, 96.f, 256.f};
__device__ __constant__ float c_hi[6] = {30.f, 60.f, 120.f, 240.f, 768.f, 768.f};

// clang-native vector types: __builtin_nontemporal_* accepts these (not HIP_vector_type)
typedef float f32x4 __attribute__((ext_vector_type(4)));
typedef float f32x2 __attribute__((ext_vector_type(2)));

__device__ __forceinline__ float4 ntload4(const float4* p) {
    f32x4 v = __builtin_nontemporal_load(reinterpret_cast<const f32x4*>(p));
    return make_float4(v.x, v.y, v.z, v.w);
}
__device__ __forceinline__ float2 ntload2(const float2* p) {
    f32x2 v = __builtin_nontemporal_load(reinterpret_cast<const f32x2*>(p));
    return make_float2(v.x, v.y);
}
__device__ __forceinline__ void ntstore4(float4 v, float4* p) {
    f32x4 x = {v.x, v.y, v.z, v.w};
    __builtin_nontemporal_store(x, reinterpret_cast<f32x4*>(p));
}

struct MatchRes { float t0, t1; int conf; };

template <int NN>
__device__ __forceinline__ MatchRes do_match_u(float center, int lvl, const float* tg) {
    float lb = c_lo[lvl], rb = c_hi[lvl];
    float best = 1e30f; int bidx = 0;
#pragma unroll
    for (int j = 0; j < NN; ++j) {
        float ts = tg[3 * j], te = tg[3 * j + 1];
        float left  = (center - ts) * 256.f;
        float right = (te - center) * 256.f;
        float md   = fmaxf(left, right);
        float area = left + right;
        bool bad = (left < 0.f) | (right < 0.f) | (md <= lb) | (md > rb);
        area = bad ? 512.f : area;
        if (area < best) { best = area; bidx = j; }   // strict < == first-occurrence argmin
    }
    MatchRes r;
    float gs = tg[3 * bidx], ge = tg[3 * bidx + 1];
    r.t0 = (center - gs) * 256.f;
    r.t1 = (ge - center) * 256.f;
    r.conf = (best >= 512.f) ? 0 : (int)tg[3 * bidx + 2];
    return r;
}

__device__ __forceinline__ MatchRes do_match_d(float center, int lvl, const float* tg, int N) {
    float lb = c_lo[lvl], rb = c_hi[lvl];
    float best = 1e30f; int bidx = 0;
    for (int j = 0; j < N; ++j) {
        float ts = tg[3 * j], te = tg[3 * j + 1];
        float left  = (center - ts) * 256.f;
        float right = (te - center) * 256.f;
        float md   = fmaxf(left, right);
        float area = left + right;
        bool bad = (left < 0.f) | (right < 0.f) | (md <= lb) | (md > rb);
        area = bad ? 512.f : area;
        if (area < best) { best = area; bidx = j; }
    }
    MatchRes r;
    float gs = tg[3 * bidx], ge = tg[3 * bidx + 1];
    r.t0 = (center - gs) * 256.f;
    r.t1 = (ge - center) * 256.f;
    r.conf = (best >= 512.f) ? 0 : (int)tg[3 * bidx + 2];
    return r;
}

__device__ __forceinline__ float calc_iou(float px, float py, float t0, float t1) {
    float inter = fminf(px, t0) + fminf(py, t1);
    float uni = px + py + t0 + t1 - inter;
    return inter / fmaxf(uni, EPSF);
}

// element i (compile-time after unroll) of a float4 array viewed as flat floats
__device__ __forceinline__ float vget(const float4* a, int i) {
    float4 x = a[i >> 2];
    int r = i & 3;
    return r == 0 ? x.x : (r == 1 ? x.y : (r == 2 ? x.z : x.w));
}

// focal over 22 classes at flat offset `base` inside an 11-float4 register block
__device__ __forceinline__ float focal22x(const float4* a, int base, int tgt) {
    float v[NCLS];
#pragma unroll
    for (int i = 0; i < NCLS; ++i) v[i] = vget(a, base + i);
    float m0 = v[0], m1 = v[1], m2 = v[2], m3 = v[3];
#pragma unroll
    for (int i = 4; i < NCLS; i += 4) {
        m0 = fmaxf(m0, v[i]);
        m1 = fmaxf(m1, v[i + 1]);
        if (i + 2 < NCLS) m2 = fmaxf(m2, v[i + 2]);
        if (i + 3 < NCLS) m3 = fmaxf(m3, v[i + 3]);
    }
    float m = fmaxf(fmaxf(m0, m1), fmaxf(m2, m3));
    float sA = 0.f, sB = 0.f, eA = 0.f, eB = 0.f;
#pragma unroll
    for (int i = 0; i < NCLS; i += 2) {
        float ea = __expf(v[i] - m);
        float eb = __expf(v[i + 1] - m);
        sA += ea; sB += eb;
        eA += (i == tgt) ? ea : 0.f;
        eB += (i + 1 == tgt) ? eb : 0.f;
    }
    float s = sA + sB;
    float pt = (eA + eB) / s + 1e-10f;
    float aa = (tgt == 0) ? 0.25f : 0.75f;
    float om = 1.f - pt;
    return -aa * om * om * __logf(pt);
}

// ---- pass 1: match + IoU for every row; per-block max of pos IoU; optional
//      store of (t0,t1,conf,iou) to wsmatch ----
__global__ __launch_bounds__(BLK) void k1_match(const float* __restrict__ loc,
                                                const float* __restrict__ priors,
                                                const float* __restrict__ targets,
                                                float* __restrict__ wsmax,
                                                float4* __restrict__ wsmatch,
                                                int K, int N) {
    int b = blockIdx.y;
    int chunk0 = blockIdx.x * K1CHUNK;
    __shared__ float tg[96];
    __shared__ float red[4];
    if (threadIdx.x < 3 * N) tg[threadIdx.x] = targets[b * 3 * N + threadIdx.x];
    __syncthreads();
    float my = -INFINITY;
    for (int it = 0; it < K1PAIRS; ++it) {
        int k0 = chunk0 + it * (BLK * 2) + threadIdx.x * 2;
        if (k0 < K) {
            size_t idx = (size_t)b * K + k0;
            float4 pr = ntload4(reinterpret_cast<const float4*>(priors) + (k0 >> 1));
            float4 lp = ntload4(reinterpret_cast<const float4*>(loc) + (idx >> 1));
            MatchRes r0 = (N == 32) ? do_match_u<32>(pr.x, (int)pr.y, tg)
                                    : do_match_d(pr.x, (int)pr.y, tg, N);
            MatchRes r1 = (N == 32) ? do_match_u<32>(pr.z, (int)pr.w, tg)
                                    : do_match_d(pr.z, (int)pr.w, tg, N);
            float i0 = calc_iou(lp.x, lp.y, r0.t0, r0.t1);
            float i1 = calc_iou(lp.z, lp.w, r1.t0, r1.t1);
            bool ok1 = (k0 + 1) < K;
            if (r0.conf > 0) my = fmaxf(my, i0);
            if (ok1 && r1.conf > 0) my = fmaxf(my, i1);
            if (wsmatch) {
                ntstore4(make_float4(r0.t0, r0.t1, (float)r0.conf, i0), wsmatch + idx);
                if (ok1)
                    ntstore4(make_float4(r1.t0, r1.t1, (float)r1.conf, i1), wsmatch + idx + 1);
            }
        }
    }
#pragma unroll
    for (int off = 32; off; off >>= 1) my = fmaxf(my, __shfl_xor(my, off));
    int wid = threadIdx.x >> 6;
    if ((threadIdx.x & 63) == 0) red[wid] = my;
    __syncthreads();
    if (threadIdx.x == 0)
        wsmax[b * gridDim.x + blockIdx.x] =
            fmaxf(fmaxf(red[0], red[1]), fmaxf(red[2], red[3]));
}

__device__ __forceinline__ void row_loss(bool act, float thr, float px, float py,
                                         float plx, float ply, float xc, float4 m,
                                         const float4* cr, int cbase,
                                         const float4* qr, int qbase,
                                         float& s_giou, float& s_sl1, float& s_bce,
                                         float& s_fc, float& s_fpc,
                                         float& c_pos, float& c_ppos) {
    float t0 = m.x, t1 = m.y; int cf = (int)m.z; float iou = m.w;
    int pc = (iou < thr) ? 0 : cf;
    float pw = px + py;
    if (act && cf > 0) {
        c_pos += 1.f;
        float inter = fminf(px, t0) + fminf(py, t1);
        float uni = px + py + t0 + t1 - inter;
        float ac = fmaxf(px, t0) + fmaxf(py, t1);
        float g = iou - (ac - uni) / fmaxf(ac, EPSF);
        s_giou += 1.f - g;
        float cl0 = 0.5f * pw * plx + px;
        float cl1 = 0.5f * pw * ply + py;
        float i2 = fminf(cl0, t0) + fminf(cl1, t1);
        float u2 = cl0 + cl1 + t0 + t1 - i2;
        float iouc = fmaxf(i2 / fmaxf(u2, EPSF), 0.f);
        float sp = fmaxf(xc, 0.f) + log1pf(__expf(-fabsf(xc)));
        s_bce += sp - xc * iouc;
    }
    if (act && pc > 0) {
        c_ppos += 1.f;
        float hpw = 0.5f * pw;
        float plt0 = (t0 - px) / hpw;
        float plt1 = (t1 - py) / hpw;
        float d0 = fabsf(plx - plt0), d1 = fabsf(ply - plt1);
        float f0 = (d0 < 1.f) ? 0.5f * d0 * d0 : d0 - 0.5f;
        float f1 = (d1 < 1.f) ? 0.5f * d1 * d1 : d1 - 0.5f;
        s_sl1 += f0 + f1;
    }
    if (act) {
        s_fc  += focal22x(cr, cbase, cf);
        s_fpc += focal22x(qr, qbase, pc);
    }
}

// ---- pass 2: per-thread row PAIR; aligned nontemporal float4 streams ----
template <bool PREM>
__global__ __launch_bounds__(BLK) void k2_loss(const float* __restrict__ loc,
                                               const float* __restrict__ conf,
                                               const float* __restrict__ ploc,
                                               const float* __restrict__ pconf,
                                               const float* __restrict__ cent,
                                               const float* __restrict__ priors,
                                               const float* __restrict__ targets,
                                               const float* __restrict__ wsmax,
                                               const float4* __restrict__ wsmatch,
                                               float* __restrict__ wspart,
                                               int K, int N, int nb1) {
    int b = blockIdx.y;
    int t = blockIdx.x * BLK + threadIdx.x;
    int k0 = t * 2;
    int wid = threadIdx.x >> 6, lane = threadIdx.x & 63;
    __shared__ float tg[96];
    __shared__ float red[7][4];
    if (!PREM) {
        if (threadIdx.x < 3 * N) tg[threadIdx.x] = targets[b * 3 * N + threadIdx.x];
        __syncthreads();
    }

    // threshold: redundant per-wave reduce of k1 block maxes (L2-broadcast, cached)
    float mx = -INFINITY;
    for (int j = lane; j < nb1; j += 64) mx = fmaxf(mx, wsmax[b * nb1 + j]);
#pragma unroll
    for (int off = 32; off; off >>= 1) mx = fmaxf(mx, __shfl_xor(mx, off));
    float thr = (mx == -INFINITY) ? 0.5f : fminf(0.5f, mx);

    bool a0 = k0 < K;
    int kc = a0 ? k0 : (K - 2);          // kc even; rows kc, kc+1 valid (K even)
    bool a1 = a0 && ((k0 + 1) < K);
    size_t idx = (size_t)b * K + kc;

    // streaming register loads: row pair = 11 float4 per tensor, all L1-bypass
    float4 c4[11], q4[11];
    {
        const float4* gc = reinterpret_cast<const float4*>(conf + idx * NCLS);
        const float4* gq = reinterpret_cast<const float4*>(pconf + idx * NCLS);
#pragma unroll
        for (int i = 0; i < 11; ++i) c4[i] = ntload4(gc + i);
#pragma unroll
        for (int i = 0; i < 11; ++i) q4[i] = ntload4(gq + i);
    }
    float4 lp = ntload4(reinterpret_cast<const float4*>(loc) + (idx >> 1));
    float4 pp = ntload4(reinterpret_cast<const float4*>(ploc) + (idx >> 1));
    float2 cc = ntload2(reinterpret_cast<const float2*>(cent) + (idx >> 1));

    float4 m0, m1;
    if (PREM) {
        m0 = ntload4(wsmatch + idx);
        m1 = ntload4(wsmatch + idx + 1);
    } else {
        float4 pr = ntload4(reinterpret_cast<const float4*>(priors) + (kc >> 1));
        MatchRes r0 = (N == 32) ? do_match_u<32>(pr.x, (int)pr.y, tg)
                                : do_match_d(pr.x, (int)pr.y, tg, N);
        MatchRes r1 = (N == 32) ? do_match_u<32>(pr.z, (int)pr.w, tg)
                                : do_match_d(pr.z, (int)pr.w, tg, N);
        m0 = make_float4(r0.t0, r0.t1, (float)r0.conf, calc_iou(lp.x, lp.y, r0.t0, r0.t1));
        m1 = make_float4(r1.t0, r1.t1, (float)r1.conf, calc_iou(lp.z, lp.w, r1.t0, r1.t1));
    }

    float s_giou = 0.f, s_sl1 = 0.f, s_bce = 0.f, s_fc = 0.f, s_fpc = 0.f,
          c_pos = 0.f, c_ppos = 0.f;
    row_loss(a0, thr, lp.x, lp.y, pp.x, pp.y, cc.x, m0, c4, 0, q4, 0,
             s_giou, s_sl1, s_bce, s_fc, s_fpc, c_pos, c_ppos);
    row_loss(a1, thr, lp.z, lp.w, pp.z, pp.w, cc.y, m1, c4, NCLS, q4, NCLS,
             s_giou, s_sl1, s_bce, s_fc, s_fpc, c_pos, c_ppos);

#pragma unroll
    for (int off = 32; off; off >>= 1) {
        s_giou += __shfl_xor(s_giou, off);
        s_sl1  += __shfl_xor(s_sl1, off);
        s_bce  += __shfl_xor(s_bce, off);
        s_fc   += __shfl_xor(s_fc, off);
        s_fpc  += __shfl_xor(s_fpc, off);
        c_pos  += __shfl_xor(c_pos, off);
        c_ppos += __shfl_xor(c_ppos, off);
    }
    if ((threadIdx.x & 63) == 0) {
        red[0][wid] = s_giou; red[1][wid] = s_sl1; red[2][wid] = s_bce;
        red[3][wid] = s_fc;   red[4][wid] = s_fpc; red[5][wid] = c_pos;
        red[6][wid] = c_ppos;
    }
    __syncthreads();
    if (threadIdx.x < 7) {
        float v = red[threadIdx.x][0] + red[threadIdx.x][1] +
                  red[threadIdx.x][2] + red[threadIdx.x][3];
        wspart[((size_t)b * gridDim.x + blockIdx.x) * 8 + threadIdx.x] = v;
    }
}

// ---- pass 3: one block, wave w = batch w ----
__global__ __launch_bounds__(512) void k3_final(const float* __restrict__ wspart,
                                                float* __restrict__ out, int B, int nb2) {
    int w = threadIdx.x >> 6, lane = threadIdx.x & 63;
    __shared__ float ls[8][5];
    float s[7] = {0.f, 0.f, 0.f, 0.f, 0.f, 0.f, 0.f};
    if (w < B) {
        for (int e = lane; e < nb2; e += 64) {
            const float* a = wspart + ((size_t)w * nb2 + e) * 8;
#pragma unroll
            for (int i = 0; i < 7; ++i) s[i] += a[i];
        }
    }
#pragma unroll
    for (int off = 32; off; off >>= 1)
#pragma unroll
        for (int i = 0; i < 7; ++i) s[i] += __shfl_xor(s[i], off);
    if (w < B && lane == 0) {
        float Nb  = fmaxf(s[5], 1.f);
        float PNb = fmaxf(s[6], 1.f);
        ls[w][0] = s[0] / Nb;    // loss_l
        ls[w][1] = s[3] / Nb;    // loss_c
        ls[w][2] = s[1] / PNb;   // loss_prop_l
        ls[w][3] = s[4] / PNb;   // loss_prop_c
        ls[w][4] = s[2] / Nb;    // loss_ct
    }
    __syncthreads();
    if (threadIdx.x < 5) {
        float tt = 0.f;
        for (int bb = 0; bb < B; ++bb) tt += ls[bb][threadIdx.x];
        out[threadIdx.x] = tt / (float)B;
    }
}

extern "C" void kernel_launch(void* const* d_in, const int* in_sizes, int n_in,
                              void* d_out, int out_size, void* d_ws, size_t ws_size,
                              hipStream_t stream) {
    const float* loc     = (const float*)d_in[0];
    const float* conf    = (const float*)d_in[1];
    const float* ploc    = (const float*)d_in[2];
    const float* pconf   = (const float*)d_in[3];
    const float* cent    = (const float*)d_in[4];
    const float* priors  = (const float*)d_in[5];
    const float* targets = (const float*)d_in[6];
    int K = in_sizes[5] / 2;
    int B = in_sizes[0] / (2 * K);
    int N = in_sizes[6] / (3 * B);
    // NCLS hardcoded to 22; K and B*K even (K=100000, B=8) — pair-alignment relies on it.

    float* wsmax  = (float*)d_ws;                           // [B * nb1] (< 1024)
    float* wspart = (float*)d_ws + 1024;                    // [B * nb2 * 8]
    const size_t match_off = (size_t)1 << 20;               // 1 MiB
    float4* wsmatch = (float4*)((char*)d_ws + match_off);   // [B * K] float4
    float* out = (float*)d_out;

    int nb1 = (K + K1CHUNK - 1) / K1CHUNK;
    int rows_per_blk = BLK * 2;
    int nb2 = (K + rows_per_blk - 1) / rows_per_blk;

    bool prem = (ws_size >= match_off + (size_t)B * K * 16) &&
                ((size_t)(1024 + B * nb2 * 8) * 4 <= match_off) &&
                (K % 2 == 0);

    k1_match<<<dim3(nb1, B), dim3(BLK), 0, stream>>>(loc, priors, targets, wsmax,
                                                     prem ? wsmatch : nullptr, K, N);
    if (prem)
        k2_loss<true><<<dim3(nb2, B), dim3(BLK), 0, stream>>>(
            loc, conf, ploc, pconf, cent, priors, targets, wsmax, wsmatch, wspart, K, N, nb1);
    else
        k2_loss<false><<<dim3(nb2, B), dim3(BLK), 0, stream>>>(
            loc, conf, ploc, pconf, cent, priors, targets, wsmax, wsmatch, wspart, K, N, nb1);
    k3_final<<<dim3(1), dim3(512), 0, stream>>>(wspart, out, B, nb2);
}

// Round 10
// 58.066 us; speedup vs baseline: 1.9052x; 1.9052x over previous
//
#include <hip/hip_runtime.h>
#include <math.h>
#include <stdint.h>

#define BLK 256
#define NCLS 22
#define ROWB 88                  // bytes per 22-float class row
#define WROWS 32                 // rows per wave
#define RPB (4 * WROWS)          // 128 rows per block
#define CH2 352                  // float2 per tensor chunk (2816 B)
#define EPSF 1.1920929e-07f
#define K1PAIRS 2
#define K1CHUNK (BLK * 2 * K1PAIRS)   // 1024 rows per k1 block

__device__ __constant__ float c_lo[6] = {0.f, 15.f, 30.f, 60.f, 96.f, 256.f};
__device__ __constant__ float c_hi[6] = {30.f, 60.f, 120.f, 240.f, 768.f, 768.f};

struct MatchRes { float t0, t1; int conf; };

template <int NN>
__device__ __forceinline__ MatchRes do_match_u(float center, int lvl, const float* tg) {
    float lb = c_lo[lvl], rb = c_hi[lvl];
    float best = 1e30f; int bidx = 0;
#pragma unroll
    for (int j = 0; j < NN; ++j) {
        float ts = tg[3 * j], te = tg[3 * j + 1];
        float left  = (center - ts) * 256.f;
        float right = (te - center) * 256.f;
        float md   = fmaxf(left, right);
        float area = left + right;
        bool bad = (left < 0.f) | (right < 0.f) | (md <= lb) | (md > rb);
        area = bad ? 512.f : area;
        if (area < best) { best = area; bidx = j; }   // strict < == first-occurrence argmin
    }
    MatchRes r;
    float gs = tg[3 * bidx], ge = tg[3 * bidx + 1];
    r.t0 = (center - gs) * 256.f;
    r.t1 = (ge - center) * 256.f;
    r.conf = (best >= 512.f) ? 0 : (int)tg[3 * bidx + 2];
    return r;
}

__device__ __forceinline__ MatchRes do_match_d(float center, int lvl, const float* tg, int N) {
    float lb = c_lo[lvl], rb = c_hi[lvl];
    float best = 1e30f; int bidx = 0;
    for (int j = 0; j < N; ++j) {
        float ts = tg[3 * j], te = tg[3 * j + 1];
        float left  = (center - ts) * 256.f;
        float right = (te - center) * 256.f;
        float md   = fmaxf(left, right);
        float area = left + right;
        bool bad = (left < 0.f) | (right < 0.f) | (md <= lb) | (md > rb);
        area = bad ? 512.f : area;
        if (area < best) { best = area; bidx = j; }
    }
    MatchRes r;
    float gs = tg[3 * bidx], ge = tg[3 * bidx + 1];
    r.t0 = (center - gs) * 256.f;
    r.t1 = (ge - center) * 256.f;
    r.conf = (best >= 512.f) ? 0 : (int)tg[3 * bidx + 2];
    return r;
}

__device__ __forceinline__ float calc_iou(float px, float py, float t0, float t1) {
    float inter = fminf(px, t0) + fminf(py, t1);
    float uni = px + py + t0 + t1 - inter;
    return inter / fmaxf(uni, EPSF);
}

__device__ __forceinline__ float fmax3(float a, float b, float c) {
    return fmaxf(fmaxf(a, b), c);   // clang fuses to v_max3_f32
}

// focal over a 22-float row in LDS; target logit via one runtime-index ds_read
__device__ __forceinline__ float focal22_lds(const float2* r2, int tgt) {
    float v[NCLS];
#pragma unroll
    for (int i = 0; i < NCLS / 2; ++i) { float2 x = r2[i]; v[2 * i] = x.x; v[2 * i + 1] = x.y; }
    float xt = reinterpret_cast<const float*>(r2)[tgt];   // 1 ds_read, no select chain
    float a0 = fmax3(v[0], v[1], v[2]),   a1 = fmax3(v[3], v[4], v[5]);
    float a2 = fmax3(v[6], v[7], v[8]),   a3 = fmax3(v[9], v[10], v[11]);
    float a4 = fmax3(v[12], v[13], v[14]), a5 = fmax3(v[15], v[16], v[17]);
    float a6 = fmax3(v[18], v[19], v[20]);
    float m = fmax3(fmax3(a0, a1, a2), fmax3(a3, a4, a5), fmaxf(a6, v[21]));
    float sA = 0.f, sB = 0.f;
#pragma unroll
    for (int i = 0; i < NCLS; i += 2) {
        sA += __expf(v[i] - m);
        sB += __expf(v[i + 1] - m);
    }
    float pt = __expf(xt - m) / (sA + sB) + 1e-10f;
    float aa = (tgt == 0) ? 0.25f : 0.75f;
    float om = 1.f - pt;
    return -aa * om * om * __logf(pt);
}

// ---- pass 1: match + IoU for every row -> wsmatch (t0,t1,conf,iou);
//      per-block max of positive IoU -> wsmax ----
__global__ __launch_bounds__(BLK) void k1_match(const float* __restrict__ loc,
                                                const float* __restrict__ priors,
                                                const float* __restrict__ targets,
                                                float* __restrict__ wsmax,
                                                float4* __restrict__ wsmatch,
                                                int K, int N) {
    int b = blockIdx.y;
    int chunk0 = blockIdx.x * K1CHUNK;
    __shared__ float tg[96];
    __shared__ float red[4];
    if (threadIdx.x < 3 * N) tg[threadIdx.x] = targets[b * 3 * N + threadIdx.x];
    __syncthreads();
    float my = -INFINITY;
    for (int it = 0; it < K1PAIRS; ++it) {
        int k0 = chunk0 + it * (BLK * 2) + threadIdx.x * 2;
        if (k0 < K) {
            size_t idx = (size_t)b * K + k0;
            float4 pr = reinterpret_cast<const float4*>(priors)[k0 >> 1];
            float4 lp = reinterpret_cast<const float4*>(loc)[idx >> 1];
            MatchRes r0 = (N == 32) ? do_match_u<32>(pr.x, (int)pr.y, tg)
                                    : do_match_d(pr.x, (int)pr.y, tg, N);
            MatchRes r1 = (N == 32) ? do_match_u<32>(pr.z, (int)pr.w, tg)
                                    : do_match_d(pr.z, (int)pr.w, tg, N);
            float i0 = calc_iou(lp.x, lp.y, r0.t0, r0.t1);
            float i1 = calc_iou(lp.z, lp.w, r1.t0, r1.t1);
            bool ok1 = (k0 + 1) < K;
            if (r0.conf > 0) my = fmaxf(my, i0);
            if (ok1 && r1.conf > 0) my = fmaxf(my, i1);
            if (wsmatch) {
                wsmatch[idx] = make_float4(r0.t0, r0.t1, (float)r0.conf, i0);
                if (ok1) wsmatch[idx + 1] = make_float4(r1.t0, r1.t1, (float)r1.conf, i1);
            }
        }
    }
#pragma unroll
    for (int off = 32; off; off >>= 1) my = fmaxf(my, __shfl_xor(my, off));
    int wid = threadIdx.x >> 6;
    if ((threadIdx.x & 63) == 0) red[wid] = my;
    __syncthreads();
    if (threadIdx.x == 0)
        wsmax[b * gridDim.x + blockIdx.x] =
            fmaxf(fmaxf(red[0], red[1]), fmaxf(red[2], red[3]));
}

// ---- pass 2: R6 dense-staged structure, match consumed from wsmatch ----
template <bool PREM>
__global__ __launch_bounds__(BLK) void k2_loss(const float* __restrict__ loc,
                                               const float* __restrict__ conf,
                                               const float* __restrict__ ploc,
                                               const float* __restrict__ pconf,
                                               const float* __restrict__ cent,
                                               const float* __restrict__ priors,
                                               const float* __restrict__ targets,
                                               const float* __restrict__ wsmax,
                                               const float4* __restrict__ wsmatch,
                                               float* __restrict__ wspart,
                                               int K, int N, int nb1) {
    int b = blockIdx.y;
    int wid = threadIdx.x >> 6, lane = threadIdx.x & 63;
    __shared__ float tg[96];
    __shared__ float red[7][4];
    __shared__ __align__(16) float2 stage[4][2 * CH2];   // per-wave conf|pconf chunk
    if (!PREM) {
        if (threadIdx.x < 3 * N) tg[threadIdx.x] = targets[b * 3 * N + threadIdx.x];
        __syncthreads();
    }

    int rb = blockIdx.x * RPB + wid * WROWS;             // wave's first row
    int rloc = lane >> 1;
    int r = rb + rloc;
    bool odd = lane & 1;
    bool act = r < K;
    int rc = act ? r : (K - 1);
    size_t idx = (size_t)b * K + rc;

    // -- small per-row register loads (issue early) --
    float w0 = (lane < nb1) ? wsmax[b * nb1 + lane] : -INFINITY;
    float w1 = (lane + 64 < nb1) ? wsmax[b * nb1 + lane + 64] : -INFINITY;
    float4 m4;
    if (PREM) m4 = wsmatch[idx];                          // (t0,t1,conf,iou)
    const float* xybase = odd ? ploc : loc;
    float2 xy = reinterpret_cast<const float2*>(xybase)[idx];   // even: lp, odd: pp
    float ccv = cent[idx];

    // -- issue dense coalesced chunk loads (3 float4/lane/tensor, clamped in-batch) --
    float4 cr[3], qr[3];
    {
        const uint8_t* cg = (const uint8_t*)conf;
        const uint8_t* qg = (const uint8_t*)pconf;
        size_t cbase = ((size_t)b * K + (size_t)(rb < K ? rb : 0)) * ROWB;
        size_t endB = ((size_t)(b + 1) * K) * ROWB - 16;   // 16-aligned (K*ROWB%16==0)
#pragma unroll
        for (int i = 0; i < 3; ++i) {
            size_t so = cbase + (size_t)i * 1024 + (size_t)lane * 16;
            if (so > endB) so = endB;
            cr[i] = *reinterpret_cast<const float4*>(cg + so);
        }
#pragma unroll
        for (int i = 0; i < 3; ++i) {
            size_t so = cbase + (size_t)i * 1024 + (size_t)lane * 16;
            if (so > endB) so = endB;
            qr[i] = *reinterpret_cast<const float4*>(qg + so);
        }
    }

    // -- compute under the loads --
    float mx = fmaxf(w0, w1);
#pragma unroll
    for (int off = 32; off; off >>= 1) mx = fmaxf(mx, __shfl_xor(mx, off));
    float thr = (mx == -INFINITY) ? 0.5f : fminf(0.5f, mx);

    float t0, t1; int cf;
    if (PREM) {
        t0 = m4.x; t1 = m4.y; cf = (int)m4.z;
    } else {
        float2 pr = reinterpret_cast<const float2*>(priors)[rc];
        MatchRes mr = (N == 32) ? do_match_u<32>(pr.x, (int)pr.y, tg)
                                : do_match_d(pr.x, (int)pr.y, tg, N);
        t0 = mr.t0; t1 = mr.t1; cf = mr.conf;
    }

    // exchange lp/pp within the lane pair
    float ox = __shfl_xor(xy.x, 1), oy = __shfl_xor(xy.y, 1);
    float lpx = odd ? ox : xy.x, lpy = odd ? oy : xy.y;
    float ppx = odd ? xy.x : ox, ppy = odd ? xy.y : oy;

    float iou = PREM ? m4.w : calc_iou(lpx, lpy, t0, t1);
    int pc = (iou < thr) ? 0 : cf;
    float pw = lpx + lpy;

    float s_giou = 0.f, s_sl1 = 0.f, s_bce = 0.f, c_pos = 0.f, c_ppos = 0.f;
    if (!odd && act && cf > 0) {          // even lane: giou + center-BCE + pos count
        c_pos = 1.f;
        float inter = fminf(lpx, t0) + fminf(lpy, t1);
        float uni = lpx + lpy + t0 + t1 - inter;
        float ac = fmaxf(lpx, t0) + fmaxf(lpy, t1);
        float g = iou - (ac - uni) / fmaxf(ac, EPSF);
        s_giou = 1.f - g;
        float cl0 = 0.5f * pw * ppx + lpx;
        float cl1 = 0.5f * pw * ppy + lpy;
        float i2 = fminf(cl0, t0) + fminf(cl1, t1);
        float u2 = cl0 + cl1 + t0 + t1 - i2;
        float iouc = fmaxf(i2 / fmaxf(u2, EPSF), 0.f);
        float sp = fmaxf(ccv, 0.f) + log1pf(__expf(-fabsf(ccv)));
        s_bce = sp - ccv * iouc;
    }
    if (odd && act && pc > 0) {           // odd lane: smooth-L1 + prop-pos count
        c_ppos = 1.f;
        float hpw = 0.5f * pw;
        float plt0 = (t0 - lpx) / hpw;
        float plt1 = (t1 - lpy) / hpw;
        float d0 = fabsf(ppx - plt0), d1 = fabsf(ppy - plt1);
        float f0 = (d0 < 1.f) ? 0.5f * d0 * d0 : d0 - 0.5f;
        float f1 = (d1 < 1.f) ? 0.5f * d1 * d1 : d1 - 0.5f;
        s_sl1 = f0 + f1;
    }

    // -- LDS staging: dense float2 writes (wave-private -> no barrier) --
    {
        float2* sb = stage[wid];
#pragma unroll
        for (int i = 0; i < 3; ++i) {
            int e2 = i * 128 + lane * 2;
            if (e2 < CH2) {                        // i=2: lanes >= 48 idle
                sb[e2]     = make_float2(cr[i].x, cr[i].y);
                sb[e2 + 1] = make_float2(cr[i].z, cr[i].w);
            }
        }
#pragma unroll
        for (int i = 0; i < 3; ++i) {
            int e2 = i * 128 + lane * 2;
            if (e2 < CH2) {
                sb[CH2 + e2]     = make_float2(qr[i].x, qr[i].y);
                sb[CH2 + e2 + 1] = make_float2(qr[i].z, qr[i].w);
            }
        }
    }
    // consumers below are LDS reads (memory ops) -> "memory" clobber orders them
    asm volatile("s_waitcnt lgkmcnt(0)" ::: "memory");

    // -- one focal per lane from the wave-private staged rows --
    const float2* rowp = stage[wid] + (odd ? CH2 : 0) + rloc * (ROWB / 8);
    int ftgt = odd ? pc : cf;
    float f = act ? focal22_lds(rowp, ftgt) : 0.f;
    float s_fc  = odd ? 0.f : f;
    float s_fpc = odd ? f : 0.f;

#pragma unroll
    for (int off = 32; off; off >>= 1) {
        s_giou += __shfl_xor(s_giou, off);
        s_sl1  += __shfl_xor(s_sl1, off);
        s_bce  += __shfl_xor(s_bce, off);
        s_fc   += __shfl_xor(s_fc, off);
        s_fpc  += __shfl_xor(s_fpc, off);
        c_pos  += __shfl_xor(c_pos, off);
        c_ppos += __shfl_xor(c_ppos, off);
    }
    if ((threadIdx.x & 63) == 0) {
        red[0][wid] = s_giou; red[1][wid] = s_sl1; red[2][wid] = s_bce;
        red[3][wid] = s_fc;   red[4][wid] = s_fpc; red[5][wid] = c_pos;
        red[6][wid] = c_ppos;
    }
    __syncthreads();
    if (threadIdx.x < 7) {
        float v = red[threadIdx.x][0] + red[threadIdx.x][1] +
                  red[threadIdx.x][2] + red[threadIdx.x][3];
        wspart[((size_t)b * gridDim.x + blockIdx.x) * 8 + threadIdx.x] = v;
    }
}

// ---- pass 3: one block, wave w = batch w ----
__global__ __launch_bounds__(512) void k3_final(const float* __restrict__ wspart,
                                                float* __restrict__ out, int B, int nb2) {
    int w = threadIdx.x >> 6, lane = threadIdx.x & 63;
    __shared__ float ls[8][5];
    float s[7] = {0.f, 0.f, 0.f, 0.f, 0.f, 0.f, 0.f};
    if (w < B) {
        for (int e = lane; e < nb2; e += 64) {
            const float* a = wspart + ((size_t)w * nb2 + e) * 8;
#pragma unroll
            for (int i = 0; i < 7; ++i) s[i] += a[i];
        }
    }
#pragma unroll
    for (int off = 32; off; off >>= 1)
#pragma unroll
        for (int i = 0; i < 7; ++i) s[i] += __shfl_xor(s[i], off);
    if (w < B && lane == 0) {
        float Nb  = fmaxf(s[5], 1.f);
        float PNb = fmaxf(s[6], 1.f);
        ls[w][0] = s[0] / Nb;    // loss_l
        ls[w][1] = s[3] / Nb;    // loss_c
        ls[w][2] = s[1] / PNb;   // loss_prop_l
        ls[w][3] = s[4] / PNb;   // loss_prop_c
        ls[w][4] = s[2] / Nb;    // loss_ct
    }
    __syncthreads();
    if (threadIdx.x < 5) {
        float tt = 0.f;
        for (int bb = 0; bb < B; ++bb) tt += ls[bb][threadIdx.x];
        out[threadIdx.x] = tt / (float)B;
    }
}

extern "C" void kernel_launch(void* const* d_in, const int* in_sizes, int n_in,
                              void* d_out, int out_size, void* d_ws, size_t ws_size,
                              hipStream_t stream) {
    const float* loc     = (const float*)d_in[0];
    const float* conf    = (const float*)d_in[1];
    const float* ploc    = (const float*)d_in[2];
    const float* pconf   = (const float*)d_in[3];
    const float* cent    = (const float*)d_in[4];
    const float* priors  = (const float*)d_in[5];
    const float* targets = (const float*)d_in[6];
    int K = in_sizes[5] / 2;
    int B = in_sizes[0] / (2 * K);
    int N = in_sizes[6] / (3 * B);
    // NCLS hardcoded to 22; K even (K=100000) — k1's paired float4 loads rely on it.

    float* wsmax  = (float*)d_ws;                           // [B * nb1] (< 1024)
    float* wspart = (float*)d_ws + 1024;                    // [B * nb2 * 8]
    const size_t match_off = (size_t)1 << 20;               // 1 MiB
    float4* wsmatch = (float4*)((char*)d_ws + match_off);   // [B * K] float4
    float* out = (float*)d_out;

    int nb1 = (K + K1CHUNK - 1) / K1CHUNK;
    int nb2 = (K + RPB - 1) / RPB;

    bool prem = (ws_size >= match_off + (size_t)B * K * 16) &&
                ((size_t)(1024 + B * nb2 * 8) * 4 <= match_off) &&
                (K % 2 == 0) && (nb1 <= 128);

    k1_match<<<dim3(nb1, B), dim3(BLK), 0, stream>>>(loc, priors, targets, wsmax,
                                                     prem ? wsmatch : nullptr, K, N);
    if (prem)
        k2_loss<true><<<dim3(nb2, B), dim3(BLK), 0, stream>>>(
            loc, conf, ploc, pconf, cent, priors, targets, wsmax, wsmatch, wspart, K, N, nb1);
    else
        k2_loss<false><<<dim3(nb2, B), dim3(BLK), 0, stream>>>(
            loc, conf, ploc, pconf, cent, priors, targets, wsmax, wsmatch, wspart, K, N, nb1);
    k3_final<<<dim3(1), dim3(512), 0, stream>>>(wspart, out, B, nb2);
}